// Round 1
// baseline (1273.326 us; speedup 1.0000x reference)
//
#include <hip/hip_runtime.h>
#include <math.h>

#define N_NODES   50000
#define N_EDGES   1600000
#define N_HEADS   8
#define IN_DIM    512
#define OUT_DIM   64
#define LRELU_A   0.2f

// ---------------------------------------------------------------------------
// GEMM: feat[node*512 + h*64 + o] = sum_k x[node*512+k] * W[h*512*64 + k*64 + o]
// 64x64 tile per block (BN=64 == one head), BK=16, 256 threads, 4x4 microtile.
// ---------------------------------------------------------------------------
__global__ __launch_bounds__(256) void gemm_feat(const float* __restrict__ x,
                                                 const float* __restrict__ W,
                                                 float* __restrict__ feat) {
    const int h  = blockIdx.y;
    const int m0 = blockIdx.x * 64;
    __shared__ float As[16][64];   // [k][m]
    __shared__ float Bs[16][64];   // [k][n]
    const int t  = threadIdx.x;
    const int tx = t & 15;         // 0..15 -> col group
    const int ty = t >> 4;         // 0..15 -> row group
    float acc[4][4] = {};
    const float* Wh = W + h * (IN_DIM * OUT_DIM);

    for (int k0 = 0; k0 < IN_DIM; k0 += 16) {
        // A tile: 64 rows x 16 k.  thread t: row=t>>2, k-offset=(t&3)*4, float4
        {
            int row = t >> 2;
            int kc  = (t & 3) * 4;
            int gm  = m0 + row;
            float4 v = make_float4(0.f, 0.f, 0.f, 0.f);
            if (gm < N_NODES) v = *(const float4*)(x + (size_t)gm * IN_DIM + k0 + kc);
            As[kc + 0][row] = v.x;
            As[kc + 1][row] = v.y;
            As[kc + 2][row] = v.z;
            As[kc + 3][row] = v.w;
        }
        // B tile: 16 k x 64 n. thread t: k=t>>4, n=(t&15)*4, float4 (coalesced)
        {
            int k = t >> 4;
            int n = (t & 15) * 4;
            float4 v = *(const float4*)(Wh + (size_t)(k0 + k) * OUT_DIM + n);
            *(float4*)&Bs[k][n] = v;
        }
        __syncthreads();
        #pragma unroll
        for (int k = 0; k < 16; ++k) {
            float4 a = *(const float4*)&As[k][ty * 4];
            float4 b = *(const float4*)&Bs[k][tx * 4];
            float av[4] = {a.x, a.y, a.z, a.w};
            float bv[4] = {b.x, b.y, b.z, b.w};
            #pragma unroll
            for (int i = 0; i < 4; ++i)
                #pragma unroll
                for (int j = 0; j < 4; ++j)
                    acc[i][j] += av[i] * bv[j];
        }
        __syncthreads();
    }
    #pragma unroll
    for (int i = 0; i < 4; ++i) {
        int gm = m0 + ty * 4 + i;
        if (gm < N_NODES) {
            float4 v = make_float4(acc[i][0], acc[i][1], acc[i][2], acc[i][3]);
            *(float4*)(feat + (size_t)gm * (N_HEADS * OUT_DIM) + h * OUT_DIM + tx * 4) = v;
        }
    }
}

// ---------------------------------------------------------------------------
// alpha_s[p] = dot(feat[p*64 + :], att_w[h*128 + 0:64])
// alpha_d[p] = dot(feat[p*64 + :], att_w[h*128 + 64:128]),  p = node*8 + h
// one wave per pair; 4 waves per block.
// ---------------------------------------------------------------------------
__global__ __launch_bounds__(256) void alpha_kernel(const float* __restrict__ feat,
                                                    const float* __restrict__ att_w,
                                                    float* __restrict__ alpha_s,
                                                    float* __restrict__ alpha_d) {
    int wid  = (blockIdx.x * blockDim.x + threadIdx.x) >> 6;
    int lane = threadIdx.x & 63;
    if (wid >= N_NODES * N_HEADS) return;
    int h   = wid & 7;
    float f = feat[(size_t)wid * 64 + lane];
    float s = f * att_w[h * 128 + lane];
    float d = f * att_w[h * 128 + 64 + lane];
    #pragma unroll
    for (int off = 32; off; off >>= 1) {
        s += __shfl_xor(s, off);
        d += __shfl_xor(d, off);
    }
    if (lane == 0) {
        alpha_s[wid] = s;
        alpha_d[wid] = d;
    }
}

// ---------------------------------------------------------------------------
// CSR build
// ---------------------------------------------------------------------------
__global__ __launch_bounds__(256) void count_kernel(const int* __restrict__ src,
                                                    int* __restrict__ cnt) {
    int e = blockIdx.x * blockDim.x + threadIdx.x;
    if (e < N_EDGES) atomicAdd(&cnt[src[e]], 1);
}

__global__ __launch_bounds__(1024) void scan_kernel(const int* __restrict__ cnt,
                                                    int* __restrict__ row_ptr,
                                                    int* __restrict__ cursor) {
    __shared__ int sh[1024];
    __shared__ int carry;
    const int t = threadIdx.x;
    if (t == 0) carry = 0;
    __syncthreads();
    for (int base = 0; base < N_NODES; base += 1024) {
        int i = base + t;
        int v = (i < N_NODES) ? cnt[i] : 0;
        sh[t] = v;
        __syncthreads();
        for (int off = 1; off < 1024; off <<= 1) {
            int tmp = (t >= off) ? sh[t - off] : 0;
            __syncthreads();
            sh[t] += tmp;
            __syncthreads();
        }
        int incl = sh[t];
        int c    = carry;
        int excl = c + incl - v;
        if (i < N_NODES) {
            row_ptr[i] = excl;
            cursor[i]  = excl;
        }
        __syncthreads();
        if (t == 0) carry += sh[1023];
        __syncthreads();
    }
    if (t == 0) row_ptr[N_NODES] = carry;
}

__global__ __launch_bounds__(256) void scatter_kernel(const int* __restrict__ src,
                                                      const int* __restrict__ dst,
                                                      int* __restrict__ cursor,
                                                      int* __restrict__ csr_dst) {
    int e = blockIdx.x * blockDim.x + threadIdx.x;
    if (e < N_EDGES) {
        int pos = atomicAdd(&cursor[src[e]], 1);
        csr_dst[pos] = dst[e];
    }
}

// ---------------------------------------------------------------------------
// Per-node softmax attention + aggregation. One block per node, wave h = head h.
// ---------------------------------------------------------------------------
__global__ __launch_bounds__(512) void agg_kernel(const float* __restrict__ feat,
                                                  const float* __restrict__ alpha_s,
                                                  const float* __restrict__ alpha_d,
                                                  const int* __restrict__ row_ptr,
                                                  const int* __restrict__ csr_dst,
                                                  float* __restrict__ out) {
    const int node = blockIdx.x;
    const int h    = threadIdx.x >> 6;
    const int lane = threadIdx.x & 63;
    const int start = row_ptr[node];
    const int deg   = row_ptr[node + 1] - start;
    const float as  = alpha_s[node * N_HEADS + h];

    // pass 1: max logit
    float m = -INFINITY;
    for (int j = lane; j < deg; j += 64) {
        int d   = csr_dst[start + j];
        float z = as + alpha_d[d * N_HEADS + h];
        z = z > 0.f ? z : LRELU_A * z;
        m = fmaxf(m, z);
    }
    #pragma unroll
    for (int off = 32; off; off >>= 1) m = fmaxf(m, __shfl_xor(m, off));

    // pass 2: denom
    float s = 0.f;
    for (int j = lane; j < deg; j += 64) {
        int d   = csr_dst[start + j];
        float z = as + alpha_d[d * N_HEADS + h];
        z = z > 0.f ? z : LRELU_A * z;
        s += __expf(z - m);
    }
    #pragma unroll
    for (int off = 32; off; off >>= 1) s += __shfl_xor(s, off);
    const float inv_denom = (deg > 0) ? 1.f / s : 0.f;

    // pass 3: weighted aggregation, chunked through LDS. lane == output dim.
    __shared__ int   dst_sh[N_HEADS][64];
    __shared__ float w_sh[N_HEADS][64];
    float acc = 0.f;
    for (int base = 0; base < deg; base += 64) {
        __syncthreads();           // deg uniform across block -> uniform syncs
        int j = base + lane;
        if (j < deg) {
            int d = csr_dst[start + j];
            dst_sh[h][lane] = d;
            float z = as + alpha_d[d * N_HEADS + h];
            z = z > 0.f ? z : LRELU_A * z;
            w_sh[h][lane] = __expf(z - m) * inv_denom;
        }
        __syncthreads();
        int cend = min(64, deg - base);
        for (int jj = 0; jj < cend; ++jj) {
            int d = dst_sh[h][jj];
            acc += w_sh[h][jj] * feat[(size_t)d * (N_HEADS * OUT_DIM) + h * OUT_DIM + lane];
        }
    }
    out[(size_t)node * (N_HEADS * OUT_DIM) + h * OUT_DIM + lane] = fmaxf(acc, 0.f);
}

// ---------------------------------------------------------------------------
extern "C" void kernel_launch(void* const* d_in, const int* in_sizes, int n_in,
                              void* d_out, int out_size, void* d_ws, size_t ws_size,
                              hipStream_t stream) {
    const float* x     = (const float*)d_in[0];
    const float* W     = (const float*)d_in[1];
    const float* att_w = (const float*)d_in[2];
    const int*   src   = (const int*)d_in[3];
    const int*   dst   = (const int*)d_in[4];
    float* out = (float*)d_out;

    // workspace layout (256B aligned regions)
    char* ws = (char*)d_ws;
    size_t off = 0;
    auto alloc = [&](size_t bytes) {
        void* p = ws + off;
        off += (bytes + 255) & ~(size_t)255;
        return p;
    };
    float* feat    = (float*)alloc((size_t)N_NODES * IN_DIM * sizeof(float));     // 102.4 MB
    float* alpha_s = (float*)alloc((size_t)N_NODES * N_HEADS * sizeof(float));
    float* alpha_d = (float*)alloc((size_t)N_NODES * N_HEADS * sizeof(float));
    int*   cnt     = (int*)alloc((size_t)N_NODES * sizeof(int));
    int*   row_ptr = (int*)alloc((size_t)(N_NODES + 1) * sizeof(int));
    int*   cursor  = (int*)alloc((size_t)N_NODES * sizeof(int));
    int*   csr_dst = (int*)alloc((size_t)N_EDGES * sizeof(int));

    hipMemsetAsync(cnt, 0, (size_t)N_NODES * sizeof(int), stream);

    dim3 ggrid((N_NODES + 63) / 64, N_HEADS);
    gemm_feat<<<ggrid, 256, 0, stream>>>(x, W, feat);

    alpha_kernel<<<(N_NODES * N_HEADS + 3) / 4, 256, 0, stream>>>(feat, att_w, alpha_s, alpha_d);

    count_kernel<<<(N_EDGES + 255) / 256, 256, 0, stream>>>(src, cnt);
    scan_kernel<<<1, 1024, 0, stream>>>(cnt, row_ptr, cursor);
    scatter_kernel<<<(N_EDGES + 255) / 256, 256, 0, stream>>>(src, dst, cursor, csr_dst);

    agg_kernel<<<N_NODES, 512, 0, stream>>>(feat, alpha_s, alpha_d, row_ptr, csr_dst, out);
}

// Round 2
// 967.343 us; speedup vs baseline: 1.3163x; 1.3163x over previous
//
#include <hip/hip_runtime.h>
#include <math.h>

#define N_NODES   50000
#define N_EDGES   1600000
#define N_HEADS   8
#define IN_DIM    512
#define OUT_DIM   64
#define FEAT_DIM  512            // N_HEADS * OUT_DIM
#define LRELU_A   0.2f
#define M_TILES   391            // ceil(50000/128)
#define M_PAD     (M_TILES*128)  // 50048 rows in xh (tail rows read but never stored)

typedef __attribute__((ext_vector_type(8))) short bf16x8;
typedef __attribute__((ext_vector_type(4))) float f32x4;

__device__ inline unsigned short f2bf(float f) {
    unsigned int u = __float_as_uint(f);
    u = (u + 0x7FFFu + ((u >> 16) & 1u)) >> 16;   // round-to-nearest-even
    return (unsigned short)u;
}

// ---------------------------------------------------------------------------
// x (fp32 [N][512]) -> xh (bf16 [M_PAD][512], rows >= N left as poison; never stored)
// ---------------------------------------------------------------------------
__global__ __launch_bounds__(256) void convert_x(const float* __restrict__ x,
                                                 unsigned short* __restrict__ xh) {
    int i = blockIdx.x * blockDim.x + threadIdx.x;   // float4 index
    if (i >= N_NODES * IN_DIM / 4) return;
    float4 v = ((const float4*)x)[i];
    ushort4 o;
    o.x = f2bf(v.x); o.y = f2bf(v.y); o.z = f2bf(v.z); o.w = f2bf(v.w);
    ((ushort4*)xh)[i] = o;
}

// ---------------------------------------------------------------------------
// W (fp32 [8][512][64]) -> Bt (bf16 [n=512][k=512]), Bt[n][k] = W[n>>6][k][n&63]
// ---------------------------------------------------------------------------
__global__ __launch_bounds__(256) void prep_b(const float* __restrict__ W,
                                              unsigned short* __restrict__ Bt) {
    int t = blockIdx.x * blockDim.x + threadIdx.x;   // t = n*512 + k
    if (t >= FEAT_DIM * IN_DIM) return;
    int n = t >> 9, k = t & 511;
    int h = n >> 6, o = n & 63;
    Bt[t] = f2bf(W[(size_t)h * IN_DIM * OUT_DIM + (size_t)k * OUT_DIM + o]);
}

// ---------------------------------------------------------------------------
// feat[m][n] = sum_k xh[m][k] * Bt[n][k]   (fp32 out)
// 128x128 tile, BK=32, 256 threads (4 waves, 2x2 wave grid of 64x64),
// mfma_f32_16x16x32_bf16, global_load_lds width-16 staging.
// A-frag: A[m=lane&15][k=(lane>>4)*8+j]; B-frag: B^T[n=lane&15][k=(lane>>4)*8+j];
// C/D: col=lane&15, row=(lane>>4)*4+reg  (verified layouts per guide §3/§5).
// ---------------------------------------------------------------------------
__global__ __launch_bounds__(256) void gemm_mfma(const unsigned short* __restrict__ xh,
                                                 const unsigned short* __restrict__ Bt,
                                                 float* __restrict__ feat) {
    __shared__ __align__(16) unsigned short As[128 * 32];  // [m][k], 64 B rows
    __shared__ __align__(16) unsigned short Bs[128 * 32];  // [n][k]
    const int t    = threadIdx.x;
    const int wid  = t >> 6;
    const int lane = t & 63;
    const int m0   = blockIdx.x * 128;
    const int n0   = blockIdx.y * 128;
    const int wm   = (wid >> 1) * 64;
    const int wn   = (wid & 1) * 64;
    const int mr   = lane & 15;
    const int q    = lane >> 4;

    f32x4 acc[4][4];
    #pragma unroll
    for (int i = 0; i < 4; ++i)
        #pragma unroll
        for (int j = 0; j < 4; ++j) acc[i][j] = 0.0f;

    const char* xb = (const char*)xh;
    const char* bb = (const char*)Bt;
    // staging geometry: tile = 8 KB = 256 thr * 16 B * 2 issues; row = 64 B
    const int o1 = t * 16;         const int row1 = o1 >> 6, kb1 = o1 & 63;
    const int o2 = t * 16 + 4096;  const int row2 = o2 >> 6, kb2 = o2 & 63;
    char* lA1 = ((char*)As) + wid * 1024;
    char* lA2 = ((char*)As) + 4096 + wid * 1024;
    char* lB1 = ((char*)Bs) + wid * 1024;
    char* lB2 = ((char*)Bs) + 4096 + wid * 1024;

    for (int k0 = 0; k0 < IN_DIM; k0 += 32) {
        const int kbyte = k0 * 2;
        __builtin_amdgcn_global_load_lds(
            (const __attribute__((address_space(1))) unsigned int*)(xb + (size_t)(m0 + row1) * (IN_DIM * 2) + kbyte + kb1),
            (__attribute__((address_space(3))) unsigned int*)lA1, 16, 0, 0);
        __builtin_amdgcn_global_load_lds(
            (const __attribute__((address_space(1))) unsigned int*)(xb + (size_t)(m0 + row2) * (IN_DIM * 2) + kbyte + kb2),
            (__attribute__((address_space(3))) unsigned int*)lA2, 16, 0, 0);
        __builtin_amdgcn_global_load_lds(
            (const __attribute__((address_space(1))) unsigned int*)(bb + (size_t)(n0 + row1) * (IN_DIM * 2) + kbyte + kb1),
            (__attribute__((address_space(3))) unsigned int*)lB1, 16, 0, 0);
        __builtin_amdgcn_global_load_lds(
            (const __attribute__((address_space(1))) unsigned int*)(bb + (size_t)(n0 + row2) * (IN_DIM * 2) + kbyte + kb2),
            (__attribute__((address_space(3))) unsigned int*)lB2, 16, 0, 0);
        __syncthreads();

        bf16x8 a[4], b[4];
        #pragma unroll
        for (int i = 0; i < 4; ++i)
            a[i] = *(const bf16x8*)&As[(wm + i * 16 + mr) * 32 + q * 8];
        #pragma unroll
        for (int j = 0; j < 4; ++j)
            b[j] = *(const bf16x8*)&Bs[(wn + j * 16 + mr) * 32 + q * 8];
        #pragma unroll
        for (int i = 0; i < 4; ++i)
            #pragma unroll
            for (int j = 0; j < 4; ++j)
                acc[i][j] = __builtin_amdgcn_mfma_f32_16x16x32_bf16(a[i], b[j], acc[i][j], 0, 0, 0);
        __syncthreads();
    }

    #pragma unroll
    for (int i = 0; i < 4; ++i) {
        #pragma unroll
        for (int j = 0; j < 4; ++j) {
            int col = n0 + wn + j * 16 + mr;
            #pragma unroll
            for (int r = 0; r < 4; ++r) {
                int row = m0 + wm + i * 16 + q * 4 + r;
                if (row < N_NODES)
                    feat[(size_t)row * FEAT_DIM + col] = acc[i][j][r];
            }
        }
    }
}

// ---------------------------------------------------------------------------
// alpha projections: one wave per (node, head)
// ---------------------------------------------------------------------------
__global__ __launch_bounds__(256) void alpha_kernel(const float* __restrict__ feat,
                                                    const float* __restrict__ att_w,
                                                    float* __restrict__ alpha_s,
                                                    float* __restrict__ alpha_d) {
    int wid  = (blockIdx.x * blockDim.x + threadIdx.x) >> 6;
    int lane = threadIdx.x & 63;
    if (wid >= N_NODES * N_HEADS) return;
    int h   = wid & 7;
    float f = feat[(size_t)wid * 64 + lane];
    float s = f * att_w[h * 128 + lane];
    float d = f * att_w[h * 128 + 64 + lane];
    #pragma unroll
    for (int off = 32; off; off >>= 1) {
        s += __shfl_xor(s, off);
        d += __shfl_xor(d, off);
    }
    if (lane == 0) {
        alpha_s[wid] = s;
        alpha_d[wid] = d;
    }
}

// ---------------------------------------------------------------------------
// CSR build
// ---------------------------------------------------------------------------
__global__ __launch_bounds__(256) void count_kernel(const int* __restrict__ src,
                                                    int* __restrict__ cnt) {
    int e = blockIdx.x * blockDim.x + threadIdx.x;
    if (e < N_EDGES) atomicAdd(&cnt[src[e]], 1);
}

// single-block wave-shuffle scan (3 barriers / 1024-tile instead of ~20)
__global__ __launch_bounds__(1024) void scan_kernel(const int* __restrict__ cnt,
                                                    int* __restrict__ row_ptr,
                                                    int* __restrict__ cursor) {
    __shared__ int wsum[16];
    const int t    = threadIdx.x;
    const int lane = t & 63;
    const int wid  = t >> 6;
    int carry = 0;
    for (int base = 0; base < N_NODES; base += 1024) {
        int i = base + t;
        int v = (i < N_NODES) ? cnt[i] : 0;
        int incl = v;
        #pragma unroll
        for (int off = 1; off < 64; off <<= 1) {
            int u = __shfl_up(incl, off);
            if (lane >= off) incl += u;
        }
        if (lane == 63) wsum[wid] = incl;
        __syncthreads();
        if (t < 16) {
            int u = wsum[t];
            #pragma unroll
            for (int off = 1; off < 16; off <<= 1) {
                int w = __shfl_up(u, off);
                if (t >= off) u += w;
            }
            wsum[t] = u;
        }
        __syncthreads();
        int woff = (wid > 0) ? wsum[wid - 1] : 0;
        int excl = carry + woff + incl - v;
        if (i < N_NODES) { row_ptr[i] = excl; cursor[i] = excl; }
        carry += wsum[15];
        __syncthreads();   // wsum reused next tile
    }
    if (t == 0) row_ptr[N_NODES] = carry;
}

__global__ __launch_bounds__(256) void scatter_kernel(const int* __restrict__ src,
                                                      const int* __restrict__ dst,
                                                      int* __restrict__ cursor,
                                                      int* __restrict__ csr_dst) {
    int e = blockIdx.x * blockDim.x + threadIdx.x;
    if (e < N_EDGES) {
        int pos = atomicAdd(&cursor[src[e]], 1);
        csr_dst[pos] = dst[e];
    }
}

// ---------------------------------------------------------------------------
// Softmax attention + aggregation. One block/node, wave h = head h.
// Pass A: fused online max+denom (1 alpha gather per edge-head).
// Pass B: chunked LDS weights; inner gather as float4 (16 lanes/edge, 4 edges
//         in flight per wave), cross-eslot shuffle reduce at the end.
// ---------------------------------------------------------------------------
__global__ __launch_bounds__(512) void agg_kernel(const float* __restrict__ feat,
                                                  const float* __restrict__ alpha_s,
                                                  const float* __restrict__ alpha_d,
                                                  const int* __restrict__ row_ptr,
                                                  const int* __restrict__ csr_dst,
                                                  float* __restrict__ out) {
    const int node = blockIdx.x;
    const int h    = threadIdx.x >> 6;
    const int lane = threadIdx.x & 63;
    const int start = row_ptr[node];
    const int deg   = row_ptr[node + 1] - start;
    const float as  = alpha_s[node * N_HEADS + h];

    // online softmax state (finite init avoids inf-inf NaNs)
    float m = -1e30f, s = 0.f;
    for (int j = lane; j < deg; j += 64) {
        int d   = csr_dst[start + j];
        float z = as + alpha_d[(size_t)d * N_HEADS + h];
        z = z > 0.f ? z : LRELU_A * z;
        float mn = fmaxf(m, z);
        s = s * __expf(m - mn) + __expf(z - mn);
        m = mn;
    }
    #pragma unroll
    for (int off = 32; off; off >>= 1) {
        float mo = __shfl_xor(m, off);
        float so = __shfl_xor(s, off);
        float mn = fmaxf(m, mo);
        s = s * __expf(m - mn) + so * __expf(mo - mn);
        m = mn;
    }
    const float inv_denom = (deg > 0) ? 1.f / s : 0.f;

    __shared__ int   dst_sh[N_HEADS][64];
    __shared__ float w_sh[N_HEADS][64];
    const int mr    = lane & 15;   // float4 slot within the 64-dim head row
    const int eslot = lane >> 4;   // which of 4 edges this lane group handles
    const float4* feat4 = (const float4*)feat;
    float4 a4 = make_float4(0.f, 0.f, 0.f, 0.f);

    for (int base = 0; base < deg; base += 64) {
        __syncthreads();
        int j = base + lane;
        if (j < deg) {
            int d = csr_dst[start + j];
            dst_sh[h][lane] = d;
            float z = as + alpha_d[(size_t)d * N_HEADS + h];
            z = z > 0.f ? z : LRELU_A * z;
            w_sh[h][lane] = __expf(z - m) * inv_denom;
        }
        __syncthreads();
        int cend = min(64, deg - base);
        for (int jj = eslot; jj < cend; jj += 4) {
            int d   = dst_sh[h][jj];
            float w = w_sh[h][jj];
            float4 f = feat4[(size_t)d * (FEAT_DIM / 4) + h * 16 + mr];
            a4.x += w * f.x; a4.y += w * f.y; a4.z += w * f.z; a4.w += w * f.w;
        }
    }
    // reduce the 4 edge-slots (lane groups 0-15 / 16-31 / 32-47 / 48-63)
    a4.x += __shfl_xor(a4.x, 16); a4.y += __shfl_xor(a4.y, 16);
    a4.z += __shfl_xor(a4.z, 16); a4.w += __shfl_xor(a4.w, 16);
    a4.x += __shfl_xor(a4.x, 32); a4.y += __shfl_xor(a4.y, 32);
    a4.z += __shfl_xor(a4.z, 32); a4.w += __shfl_xor(a4.w, 32);
    if (eslot == 0) {
        float4 o4 = make_float4(fmaxf(a4.x, 0.f), fmaxf(a4.y, 0.f),
                                fmaxf(a4.z, 0.f), fmaxf(a4.w, 0.f));
        ((float4*)out)[(size_t)node * (FEAT_DIM / 4) + h * 16 + mr] = o4;
    }
}

// ---------------------------------------------------------------------------
extern "C" void kernel_launch(void* const* d_in, const int* in_sizes, int n_in,
                              void* d_out, int out_size, void* d_ws, size_t ws_size,
                              hipStream_t stream) {
    const float* x     = (const float*)d_in[0];
    const float* W     = (const float*)d_in[1];
    const float* att_w = (const float*)d_in[2];
    const int*   src   = (const int*)d_in[3];
    const int*   dst   = (const int*)d_in[4];
    float* out = (float*)d_out;

    char* ws = (char*)d_ws;
    size_t off = 0;
    auto alloc = [&](size_t bytes) {
        void* p = ws + off;
        off += (bytes + 255) & ~(size_t)255;
        return p;
    };
    float* feat            = (float*)alloc((size_t)N_NODES * FEAT_DIM * sizeof(float));        // 102.4 MB
    unsigned short* xh     = (unsigned short*)alloc((size_t)M_PAD * IN_DIM * sizeof(short));   // 51.2 MB
    unsigned short* Bt     = (unsigned short*)alloc((size_t)FEAT_DIM * IN_DIM * sizeof(short));// 0.5 MB
    float* alpha_s = (float*)alloc((size_t)N_NODES * N_HEADS * sizeof(float));
    float* alpha_d = (float*)alloc((size_t)N_NODES * N_HEADS * sizeof(float));
    int*   cnt     = (int*)alloc((size_t)N_NODES * sizeof(int));
    int*   row_ptr = (int*)alloc((size_t)(N_NODES + 1) * sizeof(int));
    int*   cursor  = (int*)alloc((size_t)N_NODES * sizeof(int));
    int*   csr_dst = (int*)alloc((size_t)N_EDGES * sizeof(int));

    hipMemsetAsync(cnt, 0, (size_t)N_NODES * sizeof(int), stream);

    convert_x<<<(N_NODES * IN_DIM / 4 + 255) / 256, 256, 0, stream>>>(x, xh);
    prep_b<<<(FEAT_DIM * IN_DIM + 255) / 256, 256, 0, stream>>>(W, Bt);

    dim3 ggrid(M_TILES, FEAT_DIM / 128);
    gemm_mfma<<<ggrid, 256, 0, stream>>>(xh, Bt, feat);

    alpha_kernel<<<(N_NODES * N_HEADS + 3) / 4, 256, 0, stream>>>(feat, att_w, alpha_s, alpha_d);

    count_kernel<<<(N_EDGES + 255) / 256, 256, 0, stream>>>(src, cnt);
    scan_kernel<<<1, 1024, 0, stream>>>(cnt, row_ptr, cursor);
    scatter_kernel<<<(N_EDGES + 255) / 256, 256, 0, stream>>>(src, dst, cursor, csr_dst);

    agg_kernel<<<N_NODES, 512, 0, stream>>>(feat, alpha_s, alpha_d, row_ptr, csr_dst, out);
}

// Round 4
// 765.830 us; speedup vs baseline: 1.6627x; 1.2631x over previous
//
#include <hip/hip_runtime.h>
#include <math.h>

#define N_NODES   50000
#define N_EDGES   1600000
#define N_HEADS   8
#define IN_DIM    512
#define OUT_DIM   64
#define FEAT_DIM  512            // N_HEADS * OUT_DIM
#define LRELU_A   0.2f
#define M_TILES   391            // ceil(50000/128)
#define M_PAD     (M_TILES*128)  // 50048 rows in xh (tail rows read but never stored)

typedef __attribute__((ext_vector_type(8))) short bf16x8;
typedef __attribute__((ext_vector_type(4))) float f32x4;

__device__ inline unsigned short f2bf(float f) {
    unsigned int u = __float_as_uint(f);
    u = (u + 0x7FFFu + ((u >> 16) & 1u)) >> 16;   // round-to-nearest-even
    return (unsigned short)u;
}
__device__ inline float bf2f(short s) {
    return __uint_as_float(((unsigned int)(unsigned short)s) << 16);
}

// ---------------------------------------------------------------------------
// x (fp32 [N][512]) -> xh (bf16 [M_PAD][512], rows >= N left as poison; never stored)
// ---------------------------------------------------------------------------
__global__ __launch_bounds__(256) void convert_x(const float* __restrict__ x,
                                                 unsigned short* __restrict__ xh) {
    int i = blockIdx.x * blockDim.x + threadIdx.x;   // float4 index
    if (i >= N_NODES * IN_DIM / 4) return;
    float4 v = ((const float4*)x)[i];
    ushort4 o;
    o.x = f2bf(v.x); o.y = f2bf(v.y); o.z = f2bf(v.z); o.w = f2bf(v.w);
    ((ushort4*)xh)[i] = o;
}

// ---------------------------------------------------------------------------
// W (fp32 [8][512][64]) -> Bt (bf16 [n=512][k=512]), Bt[n][k] = W[n>>6][k][n&63]
// ---------------------------------------------------------------------------
__global__ __launch_bounds__(256) void prep_b(const float* __restrict__ W,
                                              unsigned short* __restrict__ Bt) {
    int t = blockIdx.x * blockDim.x + threadIdx.x;   // t = n*512 + k
    if (t >= FEAT_DIM * IN_DIM) return;
    int n = t >> 9, k = t & 511;
    int h = n >> 6, o = n & 63;
    Bt[t] = f2bf(W[(size_t)h * IN_DIM * OUT_DIM + (size_t)k * OUT_DIM + o]);
}

// ---------------------------------------------------------------------------
// feat_h[m][n] = bf16( sum_k xh[m][k] * Bt[n][k] )
// 128x128 tile, BK=32, 256 threads (4 waves, 2x2 wave grid of 64x64),
// mfma_f32_16x16x32_bf16, global_load_lds width-16 staging.
// ---------------------------------------------------------------------------
__global__ __launch_bounds__(256) void gemm_mfma(const unsigned short* __restrict__ xh,
                                                 const unsigned short* __restrict__ Bt,
                                                 unsigned short* __restrict__ feat_h) {
    __shared__ __align__(16) unsigned short As[128 * 32];  // [m][k], 64 B rows
    __shared__ __align__(16) unsigned short Bs[128 * 32];  // [n][k]
    const int t    = threadIdx.x;
    const int wid  = t >> 6;
    const int lane = t & 63;
    const int m0   = blockIdx.x * 128;
    const int n0   = blockIdx.y * 128;
    const int wm   = (wid >> 1) * 64;
    const int wn   = (wid & 1) * 64;
    const int mr   = lane & 15;
    const int q    = lane >> 4;

    f32x4 acc[4][4];
    #pragma unroll
    for (int i = 0; i < 4; ++i)
        #pragma unroll
        for (int j = 0; j < 4; ++j) acc[i][j] = 0.0f;

    const char* xb = (const char*)xh;
    const char* bb = (const char*)Bt;
    const int o1 = t * 16;         const int row1 = o1 >> 6, kb1 = o1 & 63;
    const int o2 = t * 16 + 4096;  const int row2 = o2 >> 6, kb2 = o2 & 63;
    char* lA1 = ((char*)As) + wid * 1024;
    char* lA2 = ((char*)As) + 4096 + wid * 1024;
    char* lB1 = ((char*)Bs) + wid * 1024;
    char* lB2 = ((char*)Bs) + 4096 + wid * 1024;

    for (int k0 = 0; k0 < IN_DIM; k0 += 32) {
        const int kbyte = k0 * 2;
        __builtin_amdgcn_global_load_lds(
            (const __attribute__((address_space(1))) unsigned int*)(xb + (size_t)(m0 + row1) * (IN_DIM * 2) + kbyte + kb1),
            (__attribute__((address_space(3))) unsigned int*)lA1, 16, 0, 0);
        __builtin_amdgcn_global_load_lds(
            (const __attribute__((address_space(1))) unsigned int*)(xb + (size_t)(m0 + row2) * (IN_DIM * 2) + kbyte + kb2),
            (__attribute__((address_space(3))) unsigned int*)lA2, 16, 0, 0);
        __builtin_amdgcn_global_load_lds(
            (const __attribute__((address_space(1))) unsigned int*)(bb + (size_t)(n0 + row1) * (IN_DIM * 2) + kbyte + kb1),
            (__attribute__((address_space(3))) unsigned int*)lB1, 16, 0, 0);
        __builtin_amdgcn_global_load_lds(
            (const __attribute__((address_space(1))) unsigned int*)(bb + (size_t)(n0 + row2) * (IN_DIM * 2) + kbyte + kb2),
            (__attribute__((address_space(3))) unsigned int*)lB2, 16, 0, 0);
        __syncthreads();

        bf16x8 a[4], b[4];
        #pragma unroll
        for (int i = 0; i < 4; ++i)
            a[i] = *(const bf16x8*)&As[(wm + i * 16 + mr) * 32 + q * 8];
        #pragma unroll
        for (int j = 0; j < 4; ++j)
            b[j] = *(const bf16x8*)&Bs[(wn + j * 16 + mr) * 32 + q * 8];
        #pragma unroll
        for (int i = 0; i < 4; ++i)
            #pragma unroll
            for (int j = 0; j < 4; ++j)
                acc[i][j] = __builtin_amdgcn_mfma_f32_16x16x32_bf16(a[i], b[j], acc[i][j], 0, 0, 0);
        __syncthreads();
    }

    #pragma unroll
    for (int i = 0; i < 4; ++i) {
        #pragma unroll
        for (int j = 0; j < 4; ++j) {
            int col = n0 + wn + j * 16 + mr;
            #pragma unroll
            for (int r = 0; r < 4; ++r) {
                int row = m0 + wm + i * 16 + q * 4 + r;
                if (row < N_NODES)
                    feat_h[(size_t)row * FEAT_DIM + col] = f2bf(acc[i][j][r]);
            }
        }
    }
}

// ---------------------------------------------------------------------------
// alpha projections from bf16 feat. One wave per node (all 8 heads).
// lane l loads feat_h[node][l*8 .. l*8+8) (16 B coalesced); head = l>>3.
// ---------------------------------------------------------------------------
__global__ __launch_bounds__(256) void alpha_kernel(const unsigned short* __restrict__ feat_h,
                                                    const float* __restrict__ att_w,
                                                    float* __restrict__ alpha_s,
                                                    float* __restrict__ alpha_d) {
    int node = (blockIdx.x * blockDim.x + threadIdx.x) >> 6;
    int lane = threadIdx.x & 63;
    if (node >= N_NODES) return;
    int h   = lane >> 3;
    int sub = lane & 7;
    bf16x8 f = *(const bf16x8*)&feat_h[(size_t)node * FEAT_DIM + lane * 8];
    float s = 0.f, d = 0.f;
    #pragma unroll
    for (int i = 0; i < 8; ++i) {
        float fv = bf2f(f[i]);
        s += fv * att_w[h * 128 + sub * 8 + i];
        d += fv * att_w[h * 128 + 64 + sub * 8 + i];
    }
    #pragma unroll
    for (int off = 1; off < 8; off <<= 1) {
        s += __shfl_xor(s, off);
        d += __shfl_xor(d, off);
    }
    if (sub == 0) {
        alpha_s[node * N_HEADS + h] = s;
        alpha_d[node * N_HEADS + h] = d;
    }
}

// ---------------------------------------------------------------------------
// CSR build
// ---------------------------------------------------------------------------
__global__ __launch_bounds__(256) void count_kernel(const int* __restrict__ src,
                                                    int* __restrict__ cnt) {
    int e = blockIdx.x * blockDim.x + threadIdx.x;
    if (e < N_EDGES) atomicAdd(&cnt[src[e]], 1);
}

__global__ __launch_bounds__(1024) void scan_kernel(const int* __restrict__ cnt,
                                                    int* __restrict__ row_ptr,
                                                    int* __restrict__ cursor) {
    __shared__ int wsum[16];
    const int t    = threadIdx.x;
    const int lane = t & 63;
    const int wid  = t >> 6;
    int carry = 0;
    for (int base = 0; base < N_NODES; base += 1024) {
        int i = base + t;
        int v = (i < N_NODES) ? cnt[i] : 0;
        int incl = v;
        #pragma unroll
        for (int off = 1; off < 64; off <<= 1) {
            int u = __shfl_up(incl, off);
            if (lane >= off) incl += u;
        }
        if (lane == 63) wsum[wid] = incl;
        __syncthreads();
        if (t < 16) {
            int u = wsum[t];
            #pragma unroll
            for (int off = 1; off < 16; off <<= 1) {
                int w = __shfl_up(u, off);
                if (t >= off) u += w;
            }
            wsum[t] = u;
        }
        __syncthreads();
        int woff = (wid > 0) ? wsum[wid - 1] : 0;
        int excl = carry + woff + incl - v;
        if (i < N_NODES) { row_ptr[i] = excl; cursor[i] = excl; }
        carry += wsum[15];
        __syncthreads();
    }
    if (t == 0) row_ptr[N_NODES] = carry;
}

__global__ __launch_bounds__(256) void scatter_kernel(const int* __restrict__ src,
                                                      const int* __restrict__ dst,
                                                      int* __restrict__ cursor,
                                                      int* __restrict__ csr_dst) {
    int e = blockIdx.x * blockDim.x + threadIdx.x;
    if (e < N_EDGES) {
        int pos = atomicAdd(&cursor[src[e]], 1);
        csr_dst[pos] = dst[e];
    }
}

// ---------------------------------------------------------------------------
// Softmax attention + aggregation. One block/node, wave h = head h.
// Pass A: fused online max+denom. Pass B: bf16 gather, 8 lanes/edge (16 B each),
// 8 edges in flight per wave; cross-eslot shuffle reduce; nontemporal out.
// ---------------------------------------------------------------------------
__global__ __launch_bounds__(512) void agg_kernel(const unsigned short* __restrict__ feat_h,
                                                  const float* __restrict__ alpha_s,
                                                  const float* __restrict__ alpha_d,
                                                  const int* __restrict__ row_ptr,
                                                  const int* __restrict__ csr_dst,
                                                  float* __restrict__ out) {
    const int node = blockIdx.x;
    const int h    = threadIdx.x >> 6;
    const int lane = threadIdx.x & 63;
    const int start = row_ptr[node];
    const int deg   = row_ptr[node + 1] - start;
    const float as  = alpha_s[node * N_HEADS + h];

    // online softmax (finite init avoids inf-inf NaNs)
    float m = -1e30f, s = 0.f;
    for (int j = lane; j < deg; j += 64) {
        int d   = csr_dst[start + j];
        float z = as + alpha_d[(size_t)d * N_HEADS + h];
        z = z > 0.f ? z : LRELU_A * z;
        float mn = fmaxf(m, z);
        s = s * __expf(m - mn) + __expf(z - mn);
        m = mn;
    }
    #pragma unroll
    for (int off = 32; off; off >>= 1) {
        float mo = __shfl_xor(m, off);
        float so = __shfl_xor(s, off);
        float mn = fmaxf(m, mo);
        s = s * __expf(m - mn) + so * __expf(mo - mn);
        m = mn;
    }
    const float inv_denom = (deg > 0) ? 1.f / s : 0.f;

    __shared__ int   dst_sh[N_HEADS][64];
    __shared__ float w_sh[N_HEADS][64];
    const int sub   = lane & 7;    // bf16x8 slot within the 64-dim head row
    const int eslot = lane >> 3;   // which of 8 edges this lane group handles
    float accv[8] = {};

    for (int base = 0; base < deg; base += 64) {
        __syncthreads();
        int j = base + lane;
        if (j < deg) {
            int d = csr_dst[start + j];
            dst_sh[h][lane] = d;
            float z = as + alpha_d[(size_t)d * N_HEADS + h];
            z = z > 0.f ? z : LRELU_A * z;
            w_sh[h][lane] = __expf(z - m) * inv_denom;
        }
        __syncthreads();
        int cend = min(64, deg - base);
        for (int jj = eslot; jj < cend; jj += 8) {
            int d   = dst_sh[h][jj];
            float w = w_sh[h][jj];
            bf16x8 f = *(const bf16x8*)&feat_h[(size_t)d * FEAT_DIM + h * OUT_DIM + sub * 8];
            #pragma unroll
            for (int i = 0; i < 8; ++i)
                accv[i] += w * bf2f(f[i]);
        }
    }
    // reduce the 8 edge-slots
    #pragma unroll
    for (int off = 8; off < 64; off <<= 1)
        #pragma unroll
        for (int i = 0; i < 8; ++i)
            accv[i] += __shfl_xor(accv[i], off);

    if (eslot == 0) {
        f32x4 o0 = { fmaxf(accv[0], 0.f), fmaxf(accv[1], 0.f),
                     fmaxf(accv[2], 0.f), fmaxf(accv[3], 0.f) };
        f32x4 o1 = { fmaxf(accv[4], 0.f), fmaxf(accv[5], 0.f),
                     fmaxf(accv[6], 0.f), fmaxf(accv[7], 0.f) };
        f32x4* op = (f32x4*)(out + (size_t)node * FEAT_DIM + h * OUT_DIM + sub * 8);
        __builtin_nontemporal_store(o0, op);
        __builtin_nontemporal_store(o1, op + 1);
    }
}

// ---------------------------------------------------------------------------
extern "C" void kernel_launch(void* const* d_in, const int* in_sizes, int n_in,
                              void* d_out, int out_size, void* d_ws, size_t ws_size,
                              hipStream_t stream) {
    const float* x     = (const float*)d_in[0];
    const float* W     = (const float*)d_in[1];
    const float* att_w = (const float*)d_in[2];
    const int*   src   = (const int*)d_in[3];
    const int*   dst   = (const int*)d_in[4];
    float* out = (float*)d_out;

    char* ws = (char*)d_ws;
    size_t off = 0;
    auto alloc = [&](size_t bytes) {
        void* p = ws + off;
        off += (bytes + 255) & ~(size_t)255;
        return p;
    };
    unsigned short* feat_h = (unsigned short*)alloc((size_t)N_NODES * FEAT_DIM * sizeof(short)); // 51.2 MB
    unsigned short* xh     = (unsigned short*)alloc((size_t)M_PAD * IN_DIM * sizeof(short));     // 51.2 MB
    unsigned short* Bt     = (unsigned short*)alloc((size_t)FEAT_DIM * IN_DIM * sizeof(short));  // 0.5 MB
    float* alpha_s = (float*)alloc((size_t)N_NODES * N_HEADS * sizeof(float));
    float* alpha_d = (float*)alloc((size_t)N_NODES * N_HEADS * sizeof(float));
    int*   cnt     = (int*)alloc((size_t)N_NODES * sizeof(int));
    int*   row_ptr = (int*)alloc((size_t)(N_NODES + 1) * sizeof(int));
    int*   cursor  = (int*)alloc((size_t)N_NODES * sizeof(int));
    int*   csr_dst = (int*)alloc((size_t)N_EDGES * sizeof(int));

    (void)hipMemsetAsync(cnt, 0, (size_t)N_NODES * sizeof(int), stream);

    convert_x<<<(N_NODES * IN_DIM / 4 + 255) / 256, 256, 0, stream>>>(x, xh);
    prep_b<<<(FEAT_DIM * IN_DIM + 255) / 256, 256, 0, stream>>>(W, Bt);

    dim3 ggrid(M_TILES, FEAT_DIM / 128);
    gemm_mfma<<<ggrid, 256, 0, stream>>>(xh, Bt, feat_h);

    alpha_kernel<<<(N_NODES + 3) / 4, 256, 0, stream>>>(feat_h, att_w, alpha_s, alpha_d);

    count_kernel<<<(N_EDGES + 255) / 256, 256, 0, stream>>>(src, cnt);
    scan_kernel<<<1, 1024, 0, stream>>>(cnt, row_ptr, cursor);
    scatter_kernel<<<(N_EDGES + 255) / 256, 256, 0, stream>>>(src, dst, cursor, csr_dst);

    agg_kernel<<<N_NODES, 512, 0, stream>>>(feat_h, alpha_s, alpha_d, row_ptr, csr_dst, out);
}

// Round 5
// 721.008 us; speedup vs baseline: 1.7660x; 1.0622x over previous
//
#include <hip/hip_runtime.h>
#include <math.h>

#define N_NODES   50000
#define N_EDGES   1600000
#define N_HEADS   8
#define IN_DIM    512
#define OUT_DIM   64
#define FEAT_DIM  512            // N_HEADS * OUT_DIM
#define LRELU_A   0.2f
#define M_TILES   391            // ceil(50000/128)
#define M_PAD     (M_TILES*128)  // 50048 rows in xh (tail rows read but never stored)

typedef __attribute__((ext_vector_type(8))) short bf16x8;
typedef __attribute__((ext_vector_type(4))) float f32x4;

__device__ inline unsigned short f2bf(float f) {
    unsigned int u = __float_as_uint(f);
    u = (u + 0x7FFFu + ((u >> 16) & 1u)) >> 16;   // round-to-nearest-even
    return (unsigned short)u;
}
__device__ inline float bf2f(short s) {
    return __uint_as_float(((unsigned int)(unsigned short)s) << 16);
}

// ---------------------------------------------------------------------------
// x (fp32 [N][512]) -> xh (bf16 [M_PAD][512], rows >= N left as poison; never stored)
// ---------------------------------------------------------------------------
__global__ __launch_bounds__(256) void convert_x(const float* __restrict__ x,
                                                 unsigned short* __restrict__ xh) {
    int i = blockIdx.x * blockDim.x + threadIdx.x;   // float4 index
    if (i >= N_NODES * IN_DIM / 4) return;
    float4 v = ((const float4*)x)[i];
    ushort4 o;
    o.x = f2bf(v.x); o.y = f2bf(v.y); o.z = f2bf(v.z); o.w = f2bf(v.w);
    ((ushort4*)xh)[i] = o;
}

// ---------------------------------------------------------------------------
// W (fp32 [8][512][64]) -> Bt (bf16 [n=512][k=512]), Bt[n][k] = W[n>>6][k][n&63]
// ---------------------------------------------------------------------------
__global__ __launch_bounds__(256) void prep_b(const float* __restrict__ W,
                                              unsigned short* __restrict__ Bt) {
    int t = blockIdx.x * blockDim.x + threadIdx.x;   // t = n*512 + k
    if (t >= FEAT_DIM * IN_DIM) return;
    int n = t >> 9, k = t & 511;
    int h = n >> 6, o = n & 63;
    Bt[t] = f2bf(W[(size_t)h * IN_DIM * OUT_DIM + (size_t)k * OUT_DIM + o]);
}

// ---------------------------------------------------------------------------
// feat_h[m][n] = bf16( sum_k xh[m][k] * Bt[n][k] )
// 128x128 tile, BK=32, 256 threads (4 waves, 2x2 wave grid of 64x64),
// mfma_f32_16x16x32_bf16, global_load_lds width-16 staging.
// ---------------------------------------------------------------------------
__global__ __launch_bounds__(256) void gemm_mfma(const unsigned short* __restrict__ xh,
                                                 const unsigned short* __restrict__ Bt,
                                                 unsigned short* __restrict__ feat_h) {
    __shared__ __align__(16) unsigned short As[128 * 32];  // [m][k], 64 B rows
    __shared__ __align__(16) unsigned short Bs[128 * 32];  // [n][k]
    const int t    = threadIdx.x;
    const int wid  = t >> 6;
    const int lane = t & 63;
    const int m0   = blockIdx.x * 128;
    const int n0   = blockIdx.y * 128;
    const int wm   = (wid >> 1) * 64;
    const int wn   = (wid & 1) * 64;
    const int mr   = lane & 15;
    const int q    = lane >> 4;

    f32x4 acc[4][4];
    #pragma unroll
    for (int i = 0; i < 4; ++i)
        #pragma unroll
        for (int j = 0; j < 4; ++j) acc[i][j] = 0.0f;

    const char* xb = (const char*)xh;
    const char* bb = (const char*)Bt;
    const int o1 = t * 16;         const int row1 = o1 >> 6, kb1 = o1 & 63;
    const int o2 = t * 16 + 4096;  const int row2 = o2 >> 6, kb2 = o2 & 63;
    char* lA1 = ((char*)As) + wid * 1024;
    char* lA2 = ((char*)As) + 4096 + wid * 1024;
    char* lB1 = ((char*)Bs) + wid * 1024;
    char* lB2 = ((char*)Bs) + 4096 + wid * 1024;

    for (int k0 = 0; k0 < IN_DIM; k0 += 32) {
        const int kbyte = k0 * 2;
        __builtin_amdgcn_global_load_lds(
            (const __attribute__((address_space(1))) unsigned int*)(xb + (size_t)(m0 + row1) * (IN_DIM * 2) + kbyte + kb1),
            (__attribute__((address_space(3))) unsigned int*)lA1, 16, 0, 0);
        __builtin_amdgcn_global_load_lds(
            (const __attribute__((address_space(1))) unsigned int*)(xb + (size_t)(m0 + row2) * (IN_DIM * 2) + kbyte + kb2),
            (__attribute__((address_space(3))) unsigned int*)lA2, 16, 0, 0);
        __builtin_amdgcn_global_load_lds(
            (const __attribute__((address_space(1))) unsigned int*)(bb + (size_t)(n0 + row1) * (IN_DIM * 2) + kbyte + kb1),
            (__attribute__((address_space(3))) unsigned int*)lB1, 16, 0, 0);
        __builtin_amdgcn_global_load_lds(
            (const __attribute__((address_space(1))) unsigned int*)(bb + (size_t)(n0 + row2) * (IN_DIM * 2) + kbyte + kb2),
            (__attribute__((address_space(3))) unsigned int*)lB2, 16, 0, 0);
        __syncthreads();

        bf16x8 a[4], b[4];
        #pragma unroll
        for (int i = 0; i < 4; ++i)
            a[i] = *(const bf16x8*)&As[(wm + i * 16 + mr) * 32 + q * 8];
        #pragma unroll
        for (int j = 0; j < 4; ++j)
            b[j] = *(const bf16x8*)&Bs[(wn + j * 16 + mr) * 32 + q * 8];
        #pragma unroll
        for (int i = 0; i < 4; ++i)
            #pragma unroll
            for (int j = 0; j < 4; ++j)
                acc[i][j] = __builtin_amdgcn_mfma_f32_16x16x32_bf16(a[i], b[j], acc[i][j], 0, 0, 0);
        __syncthreads();
    }

    #pragma unroll
    for (int i = 0; i < 4; ++i) {
        #pragma unroll
        for (int j = 0; j < 4; ++j) {
            int col = n0 + wn + j * 16 + mr;
            #pragma unroll
            for (int r = 0; r < 4; ++r) {
                int row = m0 + wm + i * 16 + q * 4 + r;
                if (row < N_NODES)
                    feat_h[(size_t)row * FEAT_DIM + col] = f2bf(acc[i][j][r]);
            }
        }
    }
}

// ---------------------------------------------------------------------------
// alpha projections from bf16 feat. One wave per node (all 8 heads).
// ---------------------------------------------------------------------------
__global__ __launch_bounds__(256) void alpha_kernel(const unsigned short* __restrict__ feat_h,
                                                    const float* __restrict__ att_w,
                                                    float* __restrict__ alpha_s,
                                                    float* __restrict__ alpha_d) {
    int node = (blockIdx.x * blockDim.x + threadIdx.x) >> 6;
    int lane = threadIdx.x & 63;
    if (node >= N_NODES) return;
    int h   = lane >> 3;
    int sub = lane & 7;
    bf16x8 f = *(const bf16x8*)&feat_h[(size_t)node * FEAT_DIM + lane * 8];
    float s = 0.f, d = 0.f;
    #pragma unroll
    for (int i = 0; i < 8; ++i) {
        float fv = bf2f(f[i]);
        s += fv * att_w[h * 128 + sub * 8 + i];
        d += fv * att_w[h * 128 + 64 + sub * 8 + i];
    }
    #pragma unroll
    for (int off = 1; off < 8; off <<= 1) {
        s += __shfl_xor(s, off);
        d += __shfl_xor(d, off);
    }
    if (sub == 0) {
        alpha_s[node * N_HEADS + h] = s;
        alpha_d[node * N_HEADS + h] = d;
    }
}

// ---------------------------------------------------------------------------
// CSR build
// ---------------------------------------------------------------------------
__global__ __launch_bounds__(256) void count_kernel(const int* __restrict__ src,
                                                    int* __restrict__ cnt) {
    int e = blockIdx.x * blockDim.x + threadIdx.x;
    if (e < N_EDGES) atomicAdd(&cnt[src[e]], 1);
}

__global__ __launch_bounds__(1024) void scan_kernel(const int* __restrict__ cnt,
                                                    int* __restrict__ row_ptr,
                                                    int* __restrict__ cursor) {
    __shared__ int wsum[16];
    const int t    = threadIdx.x;
    const int lane = t & 63;
    const int wid  = t >> 6;
    int carry = 0;
    for (int base = 0; base < N_NODES; base += 1024) {
        int i = base + t;
        int v = (i < N_NODES) ? cnt[i] : 0;
        int incl = v;
        #pragma unroll
        for (int off = 1; off < 64; off <<= 1) {
            int u = __shfl_up(incl, off);
            if (lane >= off) incl += u;
        }
        if (lane == 63) wsum[wid] = incl;
        __syncthreads();
        if (t < 16) {
            int u = wsum[t];
            #pragma unroll
            for (int off = 1; off < 16; off <<= 1) {
                int w = __shfl_up(u, off);
                if (t >= off) u += w;
            }
            wsum[t] = u;
        }
        __syncthreads();
        int woff = (wid > 0) ? wsum[wid - 1] : 0;
        int excl = carry + woff + incl - v;
        if (i < N_NODES) { row_ptr[i] = excl; cursor[i] = excl; }
        carry += wsum[15];
        __syncthreads();
    }
    if (t == 0) row_ptr[N_NODES] = carry;
}

__global__ __launch_bounds__(256) void scatter_kernel(const int* __restrict__ src,
                                                      const int* __restrict__ dst,
                                                      int* __restrict__ cursor,
                                                      int* __restrict__ csr_dst) {
    int e = blockIdx.x * blockDim.x + threadIdx.x;
    if (e < N_EDGES) {
        int pos = atomicAdd(&cursor[src[e]], 1);
        csr_dst[pos] = dst[e];
    }
}

// ---------------------------------------------------------------------------
// Fused single-pass attention+aggregation. One WAVE per node; lane's head =
// lane>>3. Per edge the wave gathers the full 1 KB feat row coalesced
// (64 lanes x 16 B). Unnormalized accumulation (acc += e*feat, s += e;
// divide at end) -- softmax max-subtraction dropped (|z| <= ~11, exp safe in
// fp32; e^m cancels exactly). No LDS, no barriers, no second sweep.
// Unroll-4 keeps 4 KB of gathers in flight per wave.
// ---------------------------------------------------------------------------
__global__ __launch_bounds__(256) void agg_kernel(const unsigned short* __restrict__ feat_h,
                                                  const float* __restrict__ alpha_s,
                                                  const float* __restrict__ alpha_d,
                                                  const int* __restrict__ row_ptr,
                                                  const int* __restrict__ csr_dst,
                                                  float* __restrict__ out) {
    const int node = (blockIdx.x * blockDim.x + threadIdx.x) >> 6;
    const int lane = threadIdx.x & 63;
    if (node >= N_NODES) return;
    const int h     = lane >> 3;
    const int start = row_ptr[node];
    const int deg   = row_ptr[node + 1] - start;
    const float as  = alpha_s[node * N_HEADS + h];
    const int* cd   = csr_dst + start;

    float sacc = 0.f;
    float acc[8] = {};

    int j = 0;
    for (; j + 4 <= deg; j += 4) {
        int d0 = cd[j + 0], d1 = cd[j + 1], d2 = cd[j + 2], d3 = cd[j + 3];
        float ad0 = alpha_d[d0 * N_HEADS + h];
        float ad1 = alpha_d[d1 * N_HEADS + h];
        float ad2 = alpha_d[d2 * N_HEADS + h];
        float ad3 = alpha_d[d3 * N_HEADS + h];
        bf16x8 f0 = *(const bf16x8*)&feat_h[(size_t)d0 * FEAT_DIM + lane * 8];
        bf16x8 f1 = *(const bf16x8*)&feat_h[(size_t)d1 * FEAT_DIM + lane * 8];
        bf16x8 f2 = *(const bf16x8*)&feat_h[(size_t)d2 * FEAT_DIM + lane * 8];
        bf16x8 f3 = *(const bf16x8*)&feat_h[(size_t)d3 * FEAT_DIM + lane * 8];
        float z0 = as + ad0; z0 = z0 > 0.f ? z0 : LRELU_A * z0; float e0 = __expf(z0);
        float z1 = as + ad1; z1 = z1 > 0.f ? z1 : LRELU_A * z1; float e1 = __expf(z1);
        float z2 = as + ad2; z2 = z2 > 0.f ? z2 : LRELU_A * z2; float e2 = __expf(z2);
        float z3 = as + ad3; z3 = z3 > 0.f ? z3 : LRELU_A * z3; float e3 = __expf(z3);
        sacc += (e0 + e1) + (e2 + e3);
        #pragma unroll
        for (int i = 0; i < 8; ++i) {
            acc[i] += e0 * bf2f(f0[i]);
            acc[i] += e1 * bf2f(f1[i]);
            acc[i] += e2 * bf2f(f2[i]);
            acc[i] += e3 * bf2f(f3[i]);
        }
    }
    for (; j < deg; ++j) {
        int d    = cd[j];
        float ad = alpha_d[d * N_HEADS + h];
        bf16x8 f = *(const bf16x8*)&feat_h[(size_t)d * FEAT_DIM + lane * 8];
        float z  = as + ad; z = z > 0.f ? z : LRELU_A * z;
        float e  = __expf(z);
        sacc += e;
        #pragma unroll
        for (int i = 0; i < 8; ++i)
            acc[i] += e * bf2f(f[i]);
    }

    const float inv = (deg > 0) ? 1.f / sacc : 0.f;
    f32x4 o0 = { fmaxf(acc[0] * inv, 0.f), fmaxf(acc[1] * inv, 0.f),
                 fmaxf(acc[2] * inv, 0.f), fmaxf(acc[3] * inv, 0.f) };
    f32x4 o1 = { fmaxf(acc[4] * inv, 0.f), fmaxf(acc[5] * inv, 0.f),
                 fmaxf(acc[6] * inv, 0.f), fmaxf(acc[7] * inv, 0.f) };
    f32x4* op = (f32x4*)(out + (size_t)node * FEAT_DIM + lane * 8);
    __builtin_nontemporal_store(o0, op);
    __builtin_nontemporal_store(o1, op + 1);
}

// ---------------------------------------------------------------------------
extern "C" void kernel_launch(void* const* d_in, const int* in_sizes, int n_in,
                              void* d_out, int out_size, void* d_ws, size_t ws_size,
                              hipStream_t stream) {
    const float* x     = (const float*)d_in[0];
    const float* W     = (const float*)d_in[1];
    const float* att_w = (const float*)d_in[2];
    const int*   src   = (const int*)d_in[3];
    const int*   dst   = (const int*)d_in[4];
    float* out = (float*)d_out;

    char* ws = (char*)d_ws;
    size_t off = 0;
    auto alloc = [&](size_t bytes) {
        void* p = ws + off;
        off += (bytes + 255) & ~(size_t)255;
        return p;
    };
    unsigned short* feat_h = (unsigned short*)alloc((size_t)N_NODES * FEAT_DIM * sizeof(short)); // 51.2 MB
    unsigned short* xh     = (unsigned short*)alloc((size_t)M_PAD * IN_DIM * sizeof(short));     // 51.2 MB
    unsigned short* Bt     = (unsigned short*)alloc((size_t)FEAT_DIM * IN_DIM * sizeof(short));  // 0.5 MB
    float* alpha_s = (float*)alloc((size_t)N_NODES * N_HEADS * sizeof(float));
    float* alpha_d = (float*)alloc((size_t)N_NODES * N_HEADS * sizeof(float));
    int*   cnt     = (int*)alloc((size_t)N_NODES * sizeof(int));
    int*   row_ptr = (int*)alloc((size_t)(N_NODES + 1) * sizeof(int));
    int*   cursor  = (int*)alloc((size_t)N_NODES * sizeof(int));
    int*   csr_dst = (int*)alloc((size_t)N_EDGES * sizeof(int));

    (void)hipMemsetAsync(cnt, 0, (size_t)N_NODES * sizeof(int), stream);

    convert_x<<<(N_NODES * IN_DIM / 4 + 255) / 256, 256, 0, stream>>>(x, xh);
    prep_b<<<(FEAT_DIM * IN_DIM + 255) / 256, 256, 0, stream>>>(W, Bt);

    dim3 ggrid(M_TILES, FEAT_DIM / 128);
    gemm_mfma<<<ggrid, 256, 0, stream>>>(xh, Bt, feat_h);

    alpha_kernel<<<(N_NODES + 3) / 4, 256, 0, stream>>>(feat_h, att_w, alpha_s, alpha_d);

    count_kernel<<<(N_EDGES + 255) / 256, 256, 0, stream>>>(src, cnt);
    scan_kernel<<<1, 1024, 0, stream>>>(cnt, row_ptr, cursor);
    scatter_kernel<<<(N_EDGES + 255) / 256, 256, 0, stream>>>(src, dst, cursor, csr_dst);

    agg_kernel<<<(N_NODES * 64 + 255) / 256, 256, 0, stream>>>(feat_h, alpha_s, alpha_d, row_ptr, csr_dst, out);
}